// Round 3
// baseline (155.986 us; speedup 1.0000x reference)
//
#include <hip/hip_runtime.h>
#include <vector>
#include <cmath>
#include <cstdint>

// ---------------------------------------------------------------------------
// Sparse Clebsch-Gordan tensor product, LMAX=5, TAUS=16, BATCH=256.
//
// One "job" per (l, m, pair(l1,l2)) in exact reference output order; each job
// produces 16x16=256 contiguous complex outputs per batch. 457 jobs.
// R3: grid-order swap — consecutive blocks now cover consecutive BATCHES
// (contiguous output addresses) instead of one job across all batches, so the
// resident block set writes a sequential ~35 MB window (DRAM row locality,
// orderly L3 evictions) instead of scattering 2 KB chunks over all 240 MB.
// ---------------------------------------------------------------------------

#define LMAXV 5
#define NTAU 16

static const int CUMT[7] = {0, 16, 64, 144, 256, 400, 576};
constexpr int F_ROWS   = 576;   // complex rows per batch
constexpr int NBATCH   = 256;
constexpr int BPB      = 8;     // batches per block
constexpr int NJOBS_C  = 457;

struct Job { int x_base; int y_base; int count; int coeff_off; int out_off; };

typedef float f32x2 __attribute__((ext_vector_type(2)));

// ------------------------- host-side CG table build ------------------------

static double factd(int n) { double r = 1.0; for (int i = 2; i <= n; ++i) r *= (double)i; return r; }

static double cg_coef(int j1, int m1, int j2, int m2, int j, int m) {
    if (m1 + m2 != m) return 0.0;
    double pref = std::sqrt((2.0 * j + 1.0) * factd(j + j1 - j2) * factd(j - j1 + j2) *
                            factd(j1 + j2 - j) / factd(j1 + j2 + j + 1));
    pref *= std::sqrt(factd(j + m) * factd(j - m) * factd(j1 - m1) * factd(j1 + m1) *
                      factd(j2 - m2) * factd(j2 + m2));
    int kmin = std::max(0, std::max(j2 - j - m1, j1 + m2 - j));
    int kmax = std::min(j1 + j2 - j, std::min(j1 - m1, j2 + m2));
    double s = 0.0;
    for (int k = kmin; k <= kmax; ++k) {
        s += ((k & 1) ? -1.0 : 1.0) /
             (factd(k) * factd(j1 + j2 - j - k) * factd(j1 - m1 - k) * factd(j2 + m2 - k) *
              factd(j - j2 + m1 + k) * factd(j - j1 - m2 + k));
    }
    return pref * s;
}

struct Tables { std::vector<Job> jobs; std::vector<float> coeffs; };

static const Tables& get_tables() {
    static Tables t = []() {
        Tables t;
        int jobidx = 0;
        for (int l = 0; l <= LMAXV; ++l) {
            for (int m_idx = 0; m_idx < 2 * l + 1; ++m_idx) {
                int m = m_idx - l;
                for (int l1 = 0; l1 <= LMAXV; ++l1) {
                    for (int l2 = l1; l2 <= LMAXV; ++l2) {
                        if (!(std::abs(l1 - l2) <= l && l <= l1 + l2)) continue;
                        int lo = std::max(-l1, m - l2), hi = std::min(l1, m + l2);
                        Job jb;
                        jb.count     = hi - lo + 1;                      // <= 11
                        jb.x_base    = CUMT[l1] + (lo + l1) * NTAU;      // F1 row at m1=lo
                        jb.y_base    = CUMT[l2] + (m - lo + l2) * NTAU;  // F2 row at m2=m-lo
                        jb.coeff_off = (int)t.coeffs.size();
                        jb.out_off   = jobidx * 256;
                        for (int m1 = lo; m1 <= hi; ++m1)
                            t.coeffs.push_back((float)cg_coef(l1, m1, l2, m - m1, l, m));
                        t.jobs.push_back(jb);
                        ++jobidx;
                    }
                }
            }
        }
        return t;
    }();
    return t;
}

// --------------------------------- kernel ----------------------------------

__global__ __launch_bounds__(256) void cg_tp_kernel(
    const float2* __restrict__ Fs, float2* __restrict__ out,
    const Job* __restrict__ jobs, const float* __restrict__ coeffs,
    int out_per_batch)
{
    // R3: batch-group major, job minor — consecutive blocks write consecutive
    // output addresses within a batch window.
    const int jid = blockIdx.x % NJOBS_C;
    const int bg  = blockIdx.x / NJOBS_C;
    const Job jb  = jobs[jid];

    __shared__ float sc[16];
    if (threadIdx.x < 16) {
        int k = threadIdx.x;
        sc[k] = (k < jb.count) ? coeffs[jb.coeff_off + k] : 0.0f;
    }
    __syncthreads();

    const int i   = threadIdx.x >> 4;   // tau1 channel
    const int j   = threadIdx.x & 15;   // tau2 channel
    const int cnt = jb.count;
    const int b0  = bg * BPB;

    const long x0 = (long)jb.x_base + i;   // + k*16 per term
    const long y0 = (long)jb.y_base + j;   // - k*16 per term

    float aR[BPB], aI[BPB];
    #pragma unroll
    for (int bb = 0; bb < BPB; ++bb) { aR[bb] = 0.0f; aI[bb] = 0.0f; }

    for (int k = 0; k < cnt; ++k) {
        const float c  = sc[k];
        const long  xr = x0 + (long)k * NTAU;
        const long  yr = y0 - (long)k * NTAU;
        float2 a[BPB], v[BPB];
        #pragma unroll
        for (int bb = 0; bb < BPB; ++bb) {
            const long boff = (long)(b0 + bb) * F_ROWS;
            a[bb] = Fs[boff + xr];
            v[bb] = Fs[boff + yr];
        }
        #pragma unroll
        for (int bb = 0; bb < BPB; ++bb) {
            const float tR = a[bb].x * v[bb].x - a[bb].y * v[bb].y;
            const float tI = a[bb].x * v[bb].y + a[bb].y * v[bb].x;
            aR[bb] = fmaf(c, tR, aR[bb]);
            aI[bb] = fmaf(c, tI, aI[bb]);
        }
    }

    #pragma unroll
    for (int bb = 0; bb < BPB; ++bb) {
        const long b = b0 + bb;
        f32x2 val; val.x = aR[bb]; val.y = aI[bb];
        f32x2* p = (f32x2*)(out + (size_t)b * out_per_batch + jb.out_off + threadIdx.x);
        __builtin_nontemporal_store(val, p);
    }
}

// ------------------------------ entry point --------------------------------

extern "C" void kernel_launch(void* const* d_in, const int* in_sizes, int n_in,
                              void* d_out, int out_size, void* d_ws, size_t ws_size,
                              hipStream_t stream) {
    const Tables& t = get_tables();

    char*  ws       = (char*)d_ws;
    Job*   d_jobs   = (Job*)ws;
    size_t jbytes   = t.jobs.size() * sizeof(Job);
    size_t coff     = (jbytes + 255) & ~(size_t)255;
    float* d_coeffs = (float*)(ws + coff);

    hipMemcpyAsync(d_jobs, t.jobs.data(), jbytes, hipMemcpyHostToDevice, stream);
    hipMemcpyAsync(d_coeffs, t.coeffs.data(), t.coeffs.size() * sizeof(float),
                   hipMemcpyHostToDevice, stream);

    const float2* Fs  = (const float2*)d_in[0];
    float2*       out = (float2*)d_out;
    const int out_per_batch = out_size / (NBATCH * 2);   // complex elems per batch

    const int nblocks = (int)t.jobs.size() * (NBATCH / BPB);
    cg_tp_kernel<<<nblocks, 256, 0, stream>>>(Fs, out, d_jobs, d_coeffs, out_per_batch);
}

// Round 4
// 129.350 us; speedup vs baseline: 1.2059x; 1.2059x over previous
//
#include <hip/hip_runtime.h>
#include <vector>
#include <cmath>
#include <cstdint>

// ---------------------------------------------------------------------------
// Sparse Clebsch-Gordan tensor product, LMAX=5, TAUS=16, BATCH=256.
//
// R4: continuous-store structure. Grid = 256 batches x 16 job-chunks.
// Each block (256 thr) loops over ~29 jobs; half-block (128 thr) per job;
// thread owns (i, 2jp) and (i, 2jp+1) -> one float4 NT store (16 B/lane,
// 1 KB per wave store instr, contiguous). Input slice = one batch (4.6 KB,
// L1-resident); float4 v-loads. No LDS. Long-lived waves feed the store
// queue continuously instead of 8-store bursts at wave death.
// ---------------------------------------------------------------------------

#define LMAXV 5
#define NTAU 16

static const int CUMT[7] = {0, 16, 64, 144, 256, 400, 576};
constexpr int F_ROWS  = 576;    // complex rows per batch
constexpr int NBATCH  = 256;
constexpr int NJOBS   = 457;
constexpr int NCHUNK  = 16;     // job-chunks per batch; 457 = 9*29 + 7*28

struct Job { int x_base; int y_base; int count; int coeff_off; int out_off; };

typedef float f32x4 __attribute__((ext_vector_type(4)));

// ------------------------- host-side CG table build ------------------------

static double factd(int n) { double r = 1.0; for (int i = 2; i <= n; ++i) r *= (double)i; return r; }

static double cg_coef(int j1, int m1, int j2, int m2, int j, int m) {
    if (m1 + m2 != m) return 0.0;
    double pref = std::sqrt((2.0 * j + 1.0) * factd(j + j1 - j2) * factd(j - j1 + j2) *
                            factd(j1 + j2 - j) / factd(j1 + j2 + j + 1));
    pref *= std::sqrt(factd(j + m) * factd(j - m) * factd(j1 - m1) * factd(j1 + m1) *
                      factd(j2 - m2) * factd(j2 + m2));
    int kmin = std::max(0, std::max(j2 - j - m1, j1 + m2 - j));
    int kmax = std::min(j1 + j2 - j, std::min(j1 - m1, j2 + m2));
    double s = 0.0;
    for (int k = kmin; k <= kmax; ++k) {
        s += ((k & 1) ? -1.0 : 1.0) /
             (factd(k) * factd(j1 + j2 - j - k) * factd(j1 - m1 - k) * factd(j2 + m2 - k) *
              factd(j - j2 + m1 + k) * factd(j - j1 - m2 + k));
    }
    return pref * s;
}

struct Tables { std::vector<Job> jobs; std::vector<float> coeffs; };

static const Tables& get_tables() {
    static Tables t = []() {
        Tables t;
        int jobidx = 0;
        for (int l = 0; l <= LMAXV; ++l) {
            for (int m_idx = 0; m_idx < 2 * l + 1; ++m_idx) {
                int m = m_idx - l;
                for (int l1 = 0; l1 <= LMAXV; ++l1) {
                    for (int l2 = l1; l2 <= LMAXV; ++l2) {
                        if (!(std::abs(l1 - l2) <= l && l <= l1 + l2)) continue;
                        int lo = std::max(-l1, m - l2), hi = std::min(l1, m + l2);
                        Job jb;
                        jb.count     = hi - lo + 1;                      // <= 11
                        jb.x_base    = CUMT[l1] + (lo + l1) * NTAU;      // F1 row at m1=lo
                        jb.y_base    = CUMT[l2] + (m - lo + l2) * NTAU;  // F2 row at m2=m-lo
                        jb.coeff_off = (int)t.coeffs.size();
                        jb.out_off   = jobidx * 256;                     // complex elems
                        for (int m1 = lo; m1 <= hi; ++m1)
                            t.coeffs.push_back((float)cg_coef(l1, m1, l2, m - m1, l, m));
                        t.jobs.push_back(jb);
                        ++jobidx;
                    }
                }
            }
        }
        return t;
    }();
    return t;
}

// --------------------------------- kernel ----------------------------------

__global__ __launch_bounds__(256) void cg_tp_kernel(
    const float2* __restrict__ Fs, float2* __restrict__ out,
    const Job* __restrict__ jobs, const float* __restrict__ coeffs,
    int out_per_batch)
{
    const int batch = blockIdx.x >> 4;          // /NCHUNK
    const int chunk = blockIdx.x & (NCHUNK - 1);
    const int jbase = (chunk < 9) ? chunk * 29 : 261 + (chunk - 9) * 28;
    const int jcnt  = (chunk < 9) ? 29 : 28;

    const float2* __restrict__ F  = Fs + (size_t)batch * F_ROWS;
    float2* __restrict__ outb     = out + (size_t)batch * out_per_batch;

    const int half = threadIdx.x >> 7;          // which job of the pair
    const int t    = threadIdx.x & 127;
    const int i    = t >> 3;                    // tau1 channel 0..15
    const int jp   = t & 7;                     // tau2 channel pair 0..7

    for (int it = 0; it < jcnt; it += 2) {
        const int jj = it + half;
        if (jj < jcnt) {
            const Job jb = jobs[jbase + jj];
            const int cnt = jb.count;
            int xr = jb.x_base + i;             // + k*16
            int yr = jb.y_base + 2 * jp;        // - k*16
            float aR0 = 0.f, aI0 = 0.f, aR1 = 0.f, aI1 = 0.f;
            for (int k = 0; k < cnt; ++k) {
                const float c = coeffs[jb.coeff_off + k];
                const float2 a = F[xr];
                const f32x4  v = *(const f32x4*)&F[yr];   // j=2jp, 2jp+1
                aR0 = fmaf(c, a.x * v.x - a.y * v.y, aR0);
                aI0 = fmaf(c, a.x * v.y + a.y * v.x, aI0);
                aR1 = fmaf(c, a.x * v.z - a.y * v.w, aR1);
                aI1 = fmaf(c, a.x * v.w + a.y * v.z, aI1);
                xr += NTAU; yr -= NTAU;
            }
            f32x4 val; val.x = aR0; val.y = aI0; val.z = aR1; val.w = aI1;
            f32x4* p = (f32x4*)(outb + jb.out_off + i * NTAU + 2 * jp);
            __builtin_nontemporal_store(val, p);
        }
    }
}

// ------------------------------ entry point --------------------------------

extern "C" void kernel_launch(void* const* d_in, const int* in_sizes, int n_in,
                              void* d_out, int out_size, void* d_ws, size_t ws_size,
                              hipStream_t stream) {
    const Tables& t = get_tables();

    char*  ws       = (char*)d_ws;
    Job*   d_jobs   = (Job*)ws;
    size_t jbytes   = t.jobs.size() * sizeof(Job);
    size_t coff     = (jbytes + 255) & ~(size_t)255;
    float* d_coeffs = (float*)(ws + coff);

    hipMemcpyAsync(d_jobs, t.jobs.data(), jbytes, hipMemcpyHostToDevice, stream);
    hipMemcpyAsync(d_coeffs, t.coeffs.data(), t.coeffs.size() * sizeof(float),
                   hipMemcpyHostToDevice, stream);

    const float2* Fs  = (const float2*)d_in[0];
    float2*       out = (float2*)d_out;
    const int out_per_batch = out_size / (NBATCH * 2);   // complex elems per batch

    const int nblocks = NBATCH * NCHUNK;
    cg_tp_kernel<<<nblocks, 256, 0, stream>>>(Fs, out, d_jobs, d_coeffs, out_per_batch);
}

// Round 5
// 118.045 us; speedup vs baseline: 1.3214x; 1.0958x over previous
//
#include <hip/hip_runtime.h>
#include <vector>
#include <cmath>
#include <cstdint>

// ---------------------------------------------------------------------------
// Sparse Clebsch-Gordan tensor product, LMAX=5, TAUS=16, BATCH=256.
//
// R5: fill-mimic store schedule. Output = 14,972,928 float4, written
// grid-stride (g, g+G, ...) so the device-wide instantaneous write footprint
// is a dense ~8 MB window sweeping the buffer in address order (HBM row
// locality + L2 write-back combining — the harness's fillBuffer hits 7 TB/s
// with exactly this pattern). batch and job index are wave-uniform by
// construction (58496 and 128 are multiples of 64). Regular stores (no NT).
// ---------------------------------------------------------------------------

#define LMAXV 5
#define NTAU 16

static const int CUMT[7] = {0, 16, 64, 144, 256, 400, 576};
constexpr int F_ROWS  = 576;          // complex rows per batch
constexpr int NBATCH  = 256;
constexpr uint32_t F4_PER_BATCH = 58496;                  // 457 jobs * 128 f4
constexpr uint32_t NTOT = F4_PER_BATCH * NBATCH;          // 14,972,928 f4
constexpr int GRID = 2048, BLK = 256;

struct Job { int x_base; int y_base; int count; int coeff_off; int out_off; };

typedef float f32x4 __attribute__((ext_vector_type(4)));

// ------------------------- host-side CG table build ------------------------

static double factd(int n) { double r = 1.0; for (int i = 2; i <= n; ++i) r *= (double)i; return r; }

static double cg_coef(int j1, int m1, int j2, int m2, int j, int m) {
    if (m1 + m2 != m) return 0.0;
    double pref = std::sqrt((2.0 * j + 1.0) * factd(j + j1 - j2) * factd(j - j1 + j2) *
                            factd(j1 + j2 - j) / factd(j1 + j2 + j + 1));
    pref *= std::sqrt(factd(j + m) * factd(j - m) * factd(j1 - m1) * factd(j1 + m1) *
                      factd(j2 - m2) * factd(j2 + m2));
    int kmin = std::max(0, std::max(j2 - j - m1, j1 + m2 - j));
    int kmax = std::min(j1 + j2 - j, std::min(j1 - m1, j2 + m2));
    double s = 0.0;
    for (int k = kmin; k <= kmax; ++k) {
        s += ((k & 1) ? -1.0 : 1.0) /
             (factd(k) * factd(j1 + j2 - j - k) * factd(j1 - m1 - k) * factd(j2 + m2 - k) *
              factd(j - j2 + m1 + k) * factd(j - j1 - m2 + k));
    }
    return pref * s;
}

struct Tables { std::vector<Job> jobs; std::vector<float> coeffs; };

static const Tables& get_tables() {
    static Tables t = []() {
        Tables t;
        int jobidx = 0;
        for (int l = 0; l <= LMAXV; ++l) {
            for (int m_idx = 0; m_idx < 2 * l + 1; ++m_idx) {
                int m = m_idx - l;
                for (int l1 = 0; l1 <= LMAXV; ++l1) {
                    for (int l2 = l1; l2 <= LMAXV; ++l2) {
                        if (!(std::abs(l1 - l2) <= l && l <= l1 + l2)) continue;
                        int lo = std::max(-l1, m - l2), hi = std::min(l1, m + l2);
                        Job jb;
                        jb.count     = hi - lo + 1;                      // <= 11
                        jb.x_base    = CUMT[l1] + (lo + l1) * NTAU;      // F1 row at m1=lo
                        jb.y_base    = CUMT[l2] + (m - lo + l2) * NTAU;  // F2 row at m2=m-lo
                        jb.coeff_off = (int)t.coeffs.size();
                        jb.out_off   = jobidx * 256;                     // complex elems
                        for (int m1 = lo; m1 <= hi; ++m1)
                            t.coeffs.push_back((float)cg_coef(l1, m1, l2, m - m1, l, m));
                        t.jobs.push_back(jb);
                        ++jobidx;
                    }
                }            }
        }
        return t;
    }();
    return t;
}

// --------------------------------- kernel ----------------------------------

__global__ __launch_bounds__(256) void cg_tp_kernel(
    const float2* __restrict__ Fs, f32x4* __restrict__ out,
    const Job* __restrict__ jobs, const float* __restrict__ coeffs)
{
    const uint32_t G = (uint32_t)gridDim.x * blockDim.x;
    for (uint32_t g = (uint32_t)blockIdx.x * blockDim.x + threadIdx.x; g < NTOT; g += G) {
        const uint32_t batch = g / F4_PER_BATCH;            // wave-uniform
        const uint32_t rem   = g - batch * F4_PER_BATCH;
        const uint32_t jid   = rem >> 7;                    // wave-uniform
        const uint32_t w     = rem & 127;
        const uint32_t i     = w >> 3;                      // tau1 0..15
        const uint32_t jp    = w & 7;                       // tau2 pair 0..7

        const Job jb = jobs[jid];
        const float2* __restrict__ F = Fs + (size_t)batch * F_ROWS;

        int xr = jb.x_base + (int)i;        // + k*16
        int yr = jb.y_base + 2 * (int)jp;   // - k*16
        float aR0 = 0.f, aI0 = 0.f, aR1 = 0.f, aI1 = 0.f;
        const int cnt = jb.count;
        for (int k = 0; k < cnt; ++k) {
            const float  c = coeffs[jb.coeff_off + k];
            const float2 a = F[xr];
            const f32x4  v = *(const f32x4*)&F[yr];         // j = 2jp, 2jp+1
            aR0 = fmaf(c, a.x * v.x - a.y * v.y, aR0);
            aI0 = fmaf(c, a.x * v.y + a.y * v.x, aI0);
            aR1 = fmaf(c, a.x * v.z - a.y * v.w, aR1);
            aI1 = fmaf(c, a.x * v.w + a.y * v.z, aI1);
            xr += NTAU; yr -= NTAU;
        }
        f32x4 val; val.x = aR0; val.y = aI0; val.z = aR1; val.w = aI1;
        out[g] = val;                                       // regular store
    }
}

// ------------------------------ entry point --------------------------------

extern "C" void kernel_launch(void* const* d_in, const int* in_sizes, int n_in,
                              void* d_out, int out_size, void* d_ws, size_t ws_size,
                              hipStream_t stream) {
    const Tables& t = get_tables();

    char*  ws       = (char*)d_ws;
    Job*   d_jobs   = (Job*)ws;
    size_t jbytes   = t.jobs.size() * sizeof(Job);
    size_t coff     = (jbytes + 255) & ~(size_t)255;
    float* d_coeffs = (float*)(ws + coff);

    hipMemcpyAsync(d_jobs, t.jobs.data(), jbytes, hipMemcpyHostToDevice, stream);
    hipMemcpyAsync(d_coeffs, t.coeffs.data(), t.coeffs.size() * sizeof(float),
                   hipMemcpyHostToDevice, stream);

    const float2* Fs  = (const float2*)d_in[0];
    f32x4*        out = (f32x4*)d_out;

    cg_tp_kernel<<<GRID, BLK, 0, stream>>>(Fs, out, d_jobs, d_coeffs);
}